// Round 6
// baseline (550.006 us; speedup 1.0000x reference)
//
#include <hip/hip_runtime.h>

#define LOG2E 1.44269504088896340736f

typedef _Float16 f16_t;
typedef f16_t f16x8 __attribute__((ext_vector_type(8)));
typedef f16_t f16x4 __attribute__((ext_vector_type(4)));
typedef float f32x4 __attribute__((ext_vector_type(4)));

// Problem constants: N=4096 nodes, F_in=512, F_out=128, H=8 heads.

// ---- K0a: pack adjacency (int32 0/1, 64MB) into bitmask (2MB) ----
__global__ __launch_bounds__(256) void k_pack_adj(const int* __restrict__ adj,
                                                  unsigned char* __restrict__ mask8) {
  const int t = blockIdx.x * 256 + threadIdx.x;  // 2M threads
  const int4 a = ((const int4*)adj)[t * 2];
  const int4 b = ((const int4*)adj)[t * 2 + 1];
  unsigned v = (a.x > 0) | ((a.y > 0) << 1) | ((a.z > 0) << 2) | ((a.w > 0) << 3) |
               ((b.x > 0) << 4) | ((b.y > 0) << 5) | ((b.z > 0) << 6) | ((b.w > 0) << 7);
  mask8[t] = (unsigned char)v;
}

// ---- K0b: x fp32 -> fp16 ----
__global__ __launch_bounds__(256) void k_cvt_x(const float* __restrict__ x,
                                               f16_t* __restrict__ xh) {
  const int t = blockIdx.x * 256 + threadIdx.x;
  const f32x4 a = ((const f32x4*)x)[t * 2];
  const f32x4 b = ((const f32x4*)x)[t * 2 + 1];
  f16x8 o;
#pragma unroll
  for (int i = 0; i < 4; ++i) { o[i] = (f16_t)a[i]; o[i + 4] = (f16_t)b[i]; }
  ((f16x8*)xh)[t] = o;
}

// ---- K0c: W [h][k][o] fp32 -> WT [h][o][k] fp16 ----
__global__ __launch_bounds__(256) void k_cvt_w(const float* __restrict__ W,
                                               f16_t* __restrict__ WT) {
  const int t = blockIdx.x * 256 + threadIdx.x;  // 524288
  const int k = t & 511, o = (t >> 9) & 127, h = t >> 16;
  WT[t] = (f16_t)W[((h << 9) + k) * 128 + o];
}

// ---- K1: Wh = x@W per head (fp16 MFMA). Store WhB pre-swizzled in PV
// B-fragment order; epilogue computes piecewise-exp tables
// EA=2^(fs*L), EA2=2^(0.2*fs*L), EB=2^(fd*L), EB2=2^(0.2*fd*L) as fp16.
__global__ __launch_bounds__(256) void k_gemm_wh(const f16_t* __restrict__ xh,
                                                 const f16_t* __restrict__ WT,
                                                 const float* __restrict__ a_src,
                                                 const float* __restrict__ a_dst,
                                                 f16_t* __restrict__ WhB,
                                                 f16_t* __restrict__ EA,
                                                 f16_t* __restrict__ EA2,
                                                 f16_t* __restrict__ EB,
                                                 f16_t* __restrict__ EB2) {
  const int h = blockIdx.y;
  const int n0 = blockIdx.x * 64;
  const int lane = threadIdx.x & 63;
  const int w = threadIdx.x >> 6;
  const int col = lane & 15;
  const int kg = lane >> 4;
  const f16_t* xrow = xh + (size_t)(n0 + w * 16 + col) * 512 + kg * 8;
  const f16_t* wb = WT + ((size_t)h << 16) + (size_t)col * 512 + kg * 8;
  f32x4 acc[8] = {};
  for (int kk = 0; kk < 512; kk += 32) {
    const f16x8 a = *(const f16x8*)(xrow + kk);
#pragma unroll
    for (int ot = 0; ot < 8; ++ot) {
      const f16x8 b = *(const f16x8*)(wb + ot * (16 * 512) + kk);
      acc[ot] = __builtin_amdgcn_mfma_f32_16x16x32_f16(a, b, acc[ot], 0, 0, 0);
    }
  }
  float ps[4] = {0.f, 0.f, 0.f, 0.f}, pd[4] = {0.f, 0.f, 0.f, 0.f};
#pragma unroll
  for (int ot = 0; ot < 8; ++ot) {
    const float as = a_src[h * 128 + ot * 16 + col];
    const float ad = a_dst[h * 128 + ot * 16 + col];
#pragma unroll
    for (int r = 0; r < 4; ++r) { ps[r] += acc[ot][r] * as; pd[r] += acc[ot][r] * ad; }
  }
#pragma unroll
  for (int m = 1; m < 16; m <<= 1) {
#pragma unroll
    for (int r = 0; r < 4; ++r) {
      ps[r] += __shfl_xor(ps[r], m, 64);
      pd[r] += __shfl_xor(pd[r], m, 64);
    }
  }
  const int nb = n0 + w * 16 + kg * 4;  // node index of acc[.][0]
  if (col == 0) {
#pragma unroll
    for (int r = 0; r < 4; ++r) {
      const float fs = ps[r] * LOG2E;
      const float fd = pd[r] * LOG2E;
      const int idx = h * 4096 + nb + r;
      EA[idx] = (f16_t)__builtin_amdgcn_exp2f(fs);
      EA2[idx] = (f16_t)__builtin_amdgcn_exp2f(0.2f * fs);
      EB[idx] = (f16_t)__builtin_amdgcn_exp2f(fd);
      EB2[idx] = (f16_t)__builtin_amdgcn_exp2f(0.2f * fd);
    }
  }
  // swizzled store: (h,o,j) -> WhB[((h*128+j/32)*8+o/16)*512 + ((j>>3)&3)*128 + (o&15)*8 + (j&7)]
  const int jb = nb >> 5;
  const int kgt = (nb >> 3) & 3;
  const int e0 = nb & 4;
  const size_t base = ((size_t)(h * 128 + jb) * 8) * 512 + kgt * 128 + col * 8 + e0;
#pragma unroll
  for (int ot = 0; ot < 8; ++ot) {
    f16x4 v;
#pragma unroll
    for (int r = 0; r < 4; ++r) v[r] = (f16_t)acc[ot][r];
    *(f16x4*)(WhB + base + ot * 512) = v;
  }
}

// ---- K2: masked softmax-numerator + PV partials over a j-slice ----
// Block = 4 waves, ALL sharing one j-slice B-stream (L1 reuse); wave w owns
// 16 rows. grid bx = s*512 + i*8 + h (head -> XCD round-robin, 64 i-tiles,
// S=4 slices) = 2048 blocks = 8 blocks/CU = 100% occupancy at <=64 VGPR.
// p = max(EA_i*EB_j, EA2_i*EB2_j) * m_ij; den via MFMA with ones-B.
__global__ __launch_bounds__(256, 8) void k_pv(const f16_t* __restrict__ WhB,
                                               const f16_t* __restrict__ EA,
                                               const f16_t* __restrict__ EA2,
                                               const f16_t* __restrict__ EB,
                                               const f16_t* __restrict__ EB2,
                                               const unsigned char* __restrict__ mask,
                                               f16_t* __restrict__ num_ws,
                                               float* __restrict__ den_ws) {
  __shared__ __align__(16) unsigned short lut[256][8];
  {
    const int t = threadIdx.x;
#pragma unroll
    for (int e = 0; e < 8; ++e) lut[t][e] = ((t >> e) & 1) ? 0x3C00 : 0;
  }
  __syncthreads();
  const int bx = blockIdx.x;
  const int h = bx & 7;                  // head -> XCD round-robin
  const int i0 = ((bx >> 3) & 63) * 64;  // 64-row i-tile
  const int s = bx >> 9;                 // j-slice
  const int lane = threadIdx.x & 63;
  const int w = threadIdx.x >> 6;
  const int col = lane & 15, kg = lane >> 4;
  const int rbase = i0 + w * 16;
  const int row0 = rbase + col;
  const int jbeg = s * 1024;
  const int sh = kg * 8;
  f16x8 A0s, A20s, ones;
  {
    const f16_t A0 = EA[h * 4096 + row0], A20 = EA2[h * 4096 + row0];
#pragma unroll
    for (int e = 0; e < 8; ++e) { A0s[e] = A0; A20s[e] = A20; ones[e] = (f16_t)1.0f; }
  }
  const unsigned char* m0 = mask + (size_t)row0 * 512 + (jbeg >> 3);
  const f16_t* EBp = EB + h * 4096 + jbeg + kg * 8;
  const f16_t* EB2p = EB2 + h * 4096 + jbeg + kg * 8;
  const f16_t* whB = WhB + ((size_t)h << 19) + (size_t)(jbeg >> 5) * 4096 + lane * 8;
  f32x4 acc[8] = {};
  f32x4 den = {};
  for (int g = 0; g < 8; ++g) {
    const uint4 md = *(const uint4*)(m0 + g * 16);
#pragma unroll
    for (int q = 0; q < 4; ++q) {
      const int itb = g * 4 + q;
      const f16x8 vb = *(const f16x8*)(EBp + itb * 32);
      const f16x8 vb2 = *(const f16x8*)(EB2p + itb * 32);
      const unsigned mw = (q == 0) ? md.x : (q == 1) ? md.y : (q == 2) ? md.z : md.w;
      const unsigned mb = (mw >> sh) & 255u;
      const f16x8 lm = *(const f16x8*)(&lut[mb][0]);
      const f16x8 a = __builtin_elementwise_max(A0s * vb, A20s * vb2) * lm;
      den = __builtin_amdgcn_mfma_f32_16x16x32_f16(a, ones, den, 0, 0, 0);
      const f16_t* wp = whB + (size_t)itb * 4096;
#pragma unroll
      for (int ot = 0; ot < 8; ++ot) {
        const f16x8 b = *(const f16x8*)(wp + ot * 512);
        acc[ot] = __builtin_amdgcn_mfma_f32_16x16x32_f16(a, b, acc[ot], 0, 0, 0);
      }
    }
  }
  // store partials (fp16 num, f32 den): D frag row m = kg*4+r, col n = col
  f16_t* np = num_ws + ((size_t)((s * 8 + h) * 4096) + rbase) * 128;
#pragma unroll
  for (int ot = 0; ot < 8; ++ot) {
#pragma unroll
    for (int r = 0; r < 4; ++r) {
      np[(kg * 4 + r) * 128 + ot * 16 + col] = (f16_t)acc[ot][r];
    }
  }
  if (col == 0) {
    float* dp = den_ws + (size_t)(s * 8 + h) * 4096 + rbase;
#pragma unroll
    for (int r = 0; r < 4; ++r) dp[kg * 4 + r] = den[r];
  }
}

// ---- K3: merge slices + normalize -> out[n][h*128+o] fp32 ----
__global__ __launch_bounds__(256) void k_merge(const f16_t* __restrict__ num_ws,
                                               const float* __restrict__ den_ws,
                                               float* __restrict__ out, int nslice) {
  const int g4 = (blockIdx.x * 256 + threadIdx.x) * 4;
  const int o = g4 & 127, h = (g4 >> 7) & 7, n = g4 >> 10;
  f32x4 sum = {};
  float d = 0.f;
  for (int sl = 0; sl < nslice; ++sl) {
    const f16x4 v = *(const f16x4*)(num_ws + ((size_t)((sl * 8 + h) * 4096) + n) * 128 + o);
#pragma unroll
    for (int i = 0; i < 4; ++i) sum[i] += (float)v[i];
    d += den_ws[(size_t)(sl * 8 + h) * 4096 + n];
  }
  const float inv = __builtin_amdgcn_rcpf(d);
  f32x4 r;
#pragma unroll
  for (int i = 0; i < 4; ++i) r[i] = sum[i] * inv;
  *(f32x4*)(out + g4) = r;
}

extern "C" void kernel_launch(void* const* d_in, const int* in_sizes, int n_in,
                              void* d_out, int out_size, void* d_ws, size_t ws_size,
                              hipStream_t stream) {
  const float* x = (const float*)d_in[0];
  const int* adj = (const int*)d_in[1];
  const float* W = (const float*)d_in[2];
  const float* a_src = (const float*)d_in[3];
  const float* a_dst = (const float*)d_in[4];
  float* out = (float*)d_out;
  char* ws = (char*)d_ws;
  // workspace layout (bytes):
  //   WhB   swizzled f16          : 0        .. 8388608
  //   xh    [4096][512] f16       : 8388608  .. 12582912
  //   WT    [8][128][512] f16     : 12582912 .. 13631488
  //   mask  [4096][512] u8        : 13631488 .. 15728640
  //   EA/EA2/EB/EB2 [8][4096] f16 : 15728640 .. 15990784 (4 x 64KB)
  //   den_ws [4][8][4096] f32     : 15990784 .. 16515072
  //   num_ws [4][8][4096][128] f16: 16515072 .. 50069504
  const size_t FIXED = 15990784;
  f16_t* WhB = (f16_t*)(ws);
  f16_t* xh = (f16_t*)(ws + 8388608);
  f16_t* WT = (f16_t*)(ws + 12582912);
  unsigned char* mask8 = (unsigned char*)(ws + 13631488);
  f16_t* EA = (f16_t*)(ws + 15728640);
  f16_t* EA2 = (f16_t*)(ws + 15794176);
  f16_t* EB = (f16_t*)(ws + 15859712);
  f16_t* EB2 = (f16_t*)(ws + 15925248);
  float* den_ws = (float*)(ws + FIXED);
  f16_t* num_ws = (f16_t*)(ws + FIXED + 4ull * 131072);

  k_pack_adj<<<8192, 256, 0, stream>>>(adj, mask8);
  k_cvt_x<<<1024, 256, 0, stream>>>(x, xh);
  k_cvt_w<<<2048, 256, 0, stream>>>(W, WT);
  k_gemm_wh<<<dim3(64, 8), 256, 0, stream>>>(xh, WT, a_src, a_dst, WhB, EA, EA2, EB, EB2);
  k_pv<<<2048, 256, 0, stream>>>(WhB, EA, EA2, EB, EB2, mask8, num_ws, den_ws);
  k_merge<<<4096, 256, 0, stream>>>(num_ws, den_ws, out, 4);
}

// Round 8
// 209.853 us; speedup vs baseline: 2.6209x; 2.6209x over previous
//
#include <hip/hip_runtime.h>

#define LOG2E 1.44269504088896340736f

typedef _Float16 f16_t;
typedef f16_t f16x2 __attribute__((ext_vector_type(2)));
typedef f16_t f16x4 __attribute__((ext_vector_type(4)));
typedef f16_t f16x8 __attribute__((ext_vector_type(8)));
typedef float f32x4 __attribute__((ext_vector_type(4)));

// Problem constants: N=4096 nodes, F_in=512, F_out=128, H=8 heads.

// ---- K0a: pack adjacency (int32 0/1, 64MB) into bitmask (2MB) ----
__global__ __launch_bounds__(256) void k_pack_adj(const int* __restrict__ adj,
                                                  unsigned char* __restrict__ mask8) {
  const int t = blockIdx.x * 256 + threadIdx.x;  // 2M threads
  const int4 a = ((const int4*)adj)[t * 2];
  const int4 b = ((const int4*)adj)[t * 2 + 1];
  unsigned v = (a.x > 0) | ((a.y > 0) << 1) | ((a.z > 0) << 2) | ((a.w > 0) << 3) |
               ((b.x > 0) << 4) | ((b.y > 0) << 5) | ((b.z > 0) << 6) | ((b.w > 0) << 7);
  mask8[t] = (unsigned char)v;
}

// ---- K0b: x fp32 -> fp16 ----
__global__ __launch_bounds__(256) void k_cvt_x(const float* __restrict__ x,
                                               f16_t* __restrict__ xh) {
  const int t = blockIdx.x * 256 + threadIdx.x;
  const f32x4 a = ((const f32x4*)x)[t * 2];
  const f32x4 b = ((const f32x4*)x)[t * 2 + 1];
  f16x8 o;
#pragma unroll
  for (int i = 0; i < 4; ++i) { o[i] = (f16_t)a[i]; o[i + 4] = (f16_t)b[i]; }
  ((f16x8*)xh)[t] = o;
}

// ---- K0c: W [h][k][o] fp32 -> WT [h][o][k] fp16 ----
__global__ __launch_bounds__(256) void k_cvt_w(const float* __restrict__ W,
                                               f16_t* __restrict__ WT) {
  const int t = blockIdx.x * 256 + threadIdx.x;  // 524288
  const int k = t & 511, o = (t >> 9) & 127, h = t >> 16;
  WT[t] = (f16_t)W[((h << 9) + k) * 128 + o];
}

// ---- K1: Wh = x@W per head (fp16 MFMA). Store WhB pre-swizzled in PV
// B-fragment order; epilogue computes piecewise-exp tables
// EA=2^(fs*L), EA2=2^(0.2*fs*L), EB=2^(fd*L), EB2=2^(0.2*fd*L) as fp16.
__global__ __launch_bounds__(256) void k_gemm_wh(const f16_t* __restrict__ xh,
                                                 const f16_t* __restrict__ WT,
                                                 const float* __restrict__ a_src,
                                                 const float* __restrict__ a_dst,
                                                 f16_t* __restrict__ WhB,
                                                 f16_t* __restrict__ EA,
                                                 f16_t* __restrict__ EA2,
                                                 f16_t* __restrict__ EB,
                                                 f16_t* __restrict__ EB2) {
  const int h = blockIdx.y;
  const int n0 = blockIdx.x * 64;
  const int lane = threadIdx.x & 63;
  const int w = threadIdx.x >> 6;
  const int col = lane & 15;
  const int kg = lane >> 4;
  const f16_t* xrow = xh + (size_t)(n0 + w * 16 + col) * 512 + kg * 8;
  const f16_t* wb = WT + ((size_t)h << 16) + (size_t)col * 512 + kg * 8;
  f32x4 acc[8] = {};
  for (int kk = 0; kk < 512; kk += 32) {
    const f16x8 a = *(const f16x8*)(xrow + kk);
#pragma unroll
    for (int ot = 0; ot < 8; ++ot) {
      const f16x8 b = *(const f16x8*)(wb + ot * (16 * 512) + kk);
      acc[ot] = __builtin_amdgcn_mfma_f32_16x16x32_f16(a, b, acc[ot], 0, 0, 0);
    }
  }
  float ps[4] = {0.f, 0.f, 0.f, 0.f}, pd[4] = {0.f, 0.f, 0.f, 0.f};
#pragma unroll
  for (int ot = 0; ot < 8; ++ot) {
    const float as = a_src[h * 128 + ot * 16 + col];
    const float ad = a_dst[h * 128 + ot * 16 + col];
#pragma unroll
    for (int r = 0; r < 4; ++r) { ps[r] += acc[ot][r] * as; pd[r] += acc[ot][r] * ad; }
  }
#pragma unroll
  for (int m = 1; m < 16; m <<= 1) {
#pragma unroll
    for (int r = 0; r < 4; ++r) {
      ps[r] += __shfl_xor(ps[r], m, 64);
      pd[r] += __shfl_xor(pd[r], m, 64);
    }
  }
  const int nb = n0 + w * 16 + kg * 4;  // node index of acc[.][0]
  if (col == 0) {
#pragma unroll
    for (int r = 0; r < 4; ++r) {
      const float fs = ps[r] * LOG2E;
      const float fd = pd[r] * LOG2E;
      const int idx = h * 4096 + nb + r;
      EA[idx] = (f16_t)__builtin_amdgcn_exp2f(fs);
      EA2[idx] = (f16_t)__builtin_amdgcn_exp2f(0.2f * fs);
      EB[idx] = (f16_t)__builtin_amdgcn_exp2f(fd);
      EB2[idx] = (f16_t)__builtin_amdgcn_exp2f(0.2f * fd);
    }
  }
  // swizzled store: (h,o,j) -> WhB[((h*128+j/32)*8+o/16)*512 + ((j>>3)&3)*128 + (o&15)*8 + (j&7)]
  const int jb = nb >> 5;
  const int kgt = (nb >> 3) & 3;
  const int e0 = nb & 4;
  const size_t base = ((size_t)(h * 128 + jb) * 8) * 512 + kgt * 128 + col * 8 + e0;
#pragma unroll
  for (int ot = 0; ot < 8; ++ot) {
    f16x4 v;
#pragma unroll
    for (int r = 0; r < 4; ++r) v[r] = (f16_t)acc[ot][r];
    *(f16x4*)(WhB + base + ot * 512) = v;
  }
}

// ---- K2: masked softmax-numerator + PV partials, o-split across waves ----
// Block = 4 waves sharing 64 rows; wave w owns o-quarter [w*32, w*32+32)
// (2 B-frags, each reused across 4 row-group MFMAs). All 4 waves compute
// IDENTICAL P fragments (same rows, same j-slice) -> den is wave-invariant:
// only wave 0 writes it (R7 bug was summing it across waves = 4x overcount).
// grid bx = s*512+i*8+h: 64 i-tiles x 8 heads x S=2 j-slices = 1024 blocks.
// p = max(EA_i*EB_j, EA2_i*EB2_j)*m_ij; den via v_dot2 on a-frags (no AGPR).
__global__ __launch_bounds__(256, 4) void k_pv(const f16_t* __restrict__ WhB,
                                               const f16_t* __restrict__ EA,
                                               const f16_t* __restrict__ EA2,
                                               const f16_t* __restrict__ EB,
                                               const f16_t* __restrict__ EB2,
                                               const unsigned char* __restrict__ mask,
                                               f16_t* __restrict__ num_ws,
                                               float* __restrict__ den_ws) {
  __shared__ __align__(16) unsigned short lut[256][8];
  {
    const int t = threadIdx.x;
#pragma unroll
    for (int e = 0; e < 8; ++e) lut[t][e] = ((t >> e) & 1) ? 0x3C00 : 0;
  }
  __syncthreads();
  const int bx = blockIdx.x;
  const int h = bx & 7;                  // head -> XCD round-robin
  const int i0 = ((bx >> 3) & 63) * 64;  // 64-row i-tile
  const int s = bx >> 9;                 // j-slice (0..1)
  const int lane = threadIdx.x & 63;
  const int w = threadIdx.x >> 6;        // o-quarter
  const int col = lane & 15, kg = lane >> 4;
  const int jbeg = s * 2048;
  f16x2 As[4], A2s[4];
#pragma unroll
  for (int g = 0; g < 4; ++g) {
    const f16_t a = EA[h * 4096 + i0 + g * 16 + col];
    const f16_t a2 = EA2[h * 4096 + i0 + g * 16 + col];
    As[g] = (f16x2){a, a};
    A2s[g] = (f16x2){a2, a2};
  }
  const unsigned char* mbase = mask + (size_t)(i0 + col) * 512 + kg + (jbeg >> 3);
  const f16_t* EBp = EB + h * 4096 + jbeg + kg * 8;
  const f16_t* EB2p = EB2 + h * 4096 + jbeg + kg * 8;
  const f16_t* whB = WhB + ((size_t)h << 19) + (size_t)(jbeg >> 5) * 4096 + (2 * w) * 512 + lane * 8;
  f32x4 acc[4][2] = {};
  float den_s[4] = {0.f, 0.f, 0.f, 0.f};
  const f16x2 ones2 = {(f16_t)1.0f, (f16_t)1.0f};
  for (int it = 0; it < 64; ++it) {
    const f16x8 vb = *(const f16x8*)(EBp + it * 32);
    const f16x8 vb2 = *(const f16x8*)(EB2p + it * 32);
    const f16_t* wp = whB + (size_t)it * 4096;
    const f16x8 b0 = *(const f16x8*)(wp);
    const f16x8 b1 = *(const f16x8*)(wp + 512);
    f16x8 ag[4];
#pragma unroll
    for (int g = 0; g < 4; ++g) {
      const unsigned mb = mbase[g * 8192 + it * 4];
      const f16x8 lm = *(const f16x8*)(&lut[mb][0]);
      f16x8 a;
#pragma unroll
      for (int p = 0; p < 4; ++p) {
        const f16x2 t1 = As[g] * ((const f16x2*)&vb)[p];
        const f16x2 t2 = A2s[g] * ((const f16x2*)&vb2)[p];
        ((f16x2*)&a)[p] = __builtin_elementwise_max(t1, t2) * ((const f16x2*)&lm)[p];
      }
      ag[g] = a;
#pragma unroll
      for (int p = 0; p < 4; ++p)
        den_s[g] = __builtin_amdgcn_fdot2(((const f16x2*)&a)[p], ones2, den_s[g], false);
    }
#pragma unroll
    for (int g = 0; g < 4; ++g) {
      acc[g][0] = __builtin_amdgcn_mfma_f32_16x16x32_f16(ag[g], b0, acc[g][0], 0, 0, 0);
      acc[g][1] = __builtin_amdgcn_mfma_f32_16x16x32_f16(ag[g], b1, acc[g][1], 0, 0, 0);
    }
  }
  // den: identical across waves; reduce over kg within wave 0 and store once.
#pragma unroll
  for (int g = 0; g < 4; ++g) {
    float d = den_s[g];
    d += __shfl_xor(d, 16, 64);
    d += __shfl_xor(d, 32, 64);
    if (w == 0 && kg == 0) {
      den_ws[(size_t)(s * 8 + h) * 4096 + i0 + g * 16 + col] = d;
    }
  }
  // num partials: D frag row = g*16 + kg*4 + r, col o = w*32 + t*16 + col
  f16_t* np = num_ws + ((size_t)(s * 8 + h) * 4096 + i0) * 128;
#pragma unroll
  for (int g = 0; g < 4; ++g) {
#pragma unroll
    for (int t = 0; t < 2; ++t) {
#pragma unroll
      for (int r = 0; r < 4; ++r) {
        np[(g * 16 + kg * 4 + r) * 128 + w * 32 + t * 16 + col] = (f16_t)acc[g][t][r];
      }
    }
  }
}

// ---- K3: merge slices + normalize -> out[n][h*128+o] fp32 ----
__global__ __launch_bounds__(256) void k_merge(const f16_t* __restrict__ num_ws,
                                               const float* __restrict__ den_ws,
                                               float* __restrict__ out, int nslice) {
  const int g4 = (blockIdx.x * 256 + threadIdx.x) * 4;
  const int o = g4 & 127, h = (g4 >> 7) & 7, n = g4 >> 10;
  f32x4 sum = {};
  float d = 0.f;
  for (int sl = 0; sl < nslice; ++sl) {
    const f16x4 v = *(const f16x4*)(num_ws + ((size_t)((sl * 8 + h) * 4096) + n) * 128 + o);
#pragma unroll
    for (int i = 0; i < 4; ++i) sum[i] += (float)v[i];
    d += den_ws[(size_t)(sl * 8 + h) * 4096 + n];
  }
  const float inv = __builtin_amdgcn_rcpf(d);
  f32x4 r;
#pragma unroll
  for (int i = 0; i < 4; ++i) r[i] = sum[i] * inv;
  *(f32x4*)(out + g4) = r;
}

extern "C" void kernel_launch(void* const* d_in, const int* in_sizes, int n_in,
                              void* d_out, int out_size, void* d_ws, size_t ws_size,
                              hipStream_t stream) {
  const float* x = (const float*)d_in[0];
  const int* adj = (const int*)d_in[1];
  const float* W = (const float*)d_in[2];
  const float* a_src = (const float*)d_in[3];
  const float* a_dst = (const float*)d_in[4];
  float* out = (float*)d_out;
  char* ws = (char*)d_ws;
  // workspace layout (bytes):
  //   WhB   swizzled f16          : 0        .. 8388608
  //   xh    [4096][512] f16       : 8388608  .. 12582912
  //   WT    [8][128][512] f16     : 12582912 .. 13631488
  //   mask  [4096][512] u8        : 13631488 .. 15728640
  //   EA/EA2/EB/EB2 [8][4096] f16 : 15728640 .. 15990784 (4 x 64KB)
  //   den_ws [2][8][4096] f32     : 15990784 .. 16252928
  //   num_ws [2][8][4096][128] f16: 16252928 .. 33030144
  const size_t FIXED = 15990784;
  f16_t* WhB = (f16_t*)(ws);
  f16_t* xh = (f16_t*)(ws + 8388608);
  f16_t* WT = (f16_t*)(ws + 12582912);
  unsigned char* mask8 = (unsigned char*)(ws + 13631488);
  f16_t* EA = (f16_t*)(ws + 15728640);
  f16_t* EA2 = (f16_t*)(ws + 15794176);
  f16_t* EB = (f16_t*)(ws + 15859712);
  f16_t* EB2 = (f16_t*)(ws + 15925248);
  float* den_ws = (float*)(ws + FIXED);
  f16_t* num_ws = (f16_t*)(ws + FIXED + 262144);

  k_pack_adj<<<8192, 256, 0, stream>>>(adj, mask8);
  k_cvt_x<<<1024, 256, 0, stream>>>(x, xh);
  k_cvt_w<<<2048, 256, 0, stream>>>(W, WT);
  k_gemm_wh<<<dim3(64, 8), 256, 0, stream>>>(xh, WT, a_src, a_dst, WhB, EA, EA2, EB, EB2);
  k_pv<<<1024, 256, 0, stream>>>(WhB, EA, EA2, EB, EB2, mask8, num_ws, den_ws);
  k_merge<<<4096, 256, 0, stream>>>(num_ws, den_ws, out, 2);
}

// Round 9
// 147.159 us; speedup vs baseline: 3.7375x; 1.4260x over previous
//
#include <hip/hip_runtime.h>

#define LOG2E 1.44269504088896340736f

typedef _Float16 f16_t;
typedef f16_t f16x2 __attribute__((ext_vector_type(2)));
typedef f16_t f16x4 __attribute__((ext_vector_type(4)));
typedef f16_t f16x8 __attribute__((ext_vector_type(8)));
typedef float f32x4 __attribute__((ext_vector_type(4)));

// Problem constants: N=4096 nodes, F_in=512, F_out=128, H=8 heads.

// ---- K0a: pack adjacency (int32 0/1, 64MB) into bitmask (2MB) ----
__global__ __launch_bounds__(256) void k_pack_adj(const int* __restrict__ adj,
                                                  unsigned char* __restrict__ mask8) {
  const int t = blockIdx.x * 256 + threadIdx.x;  // 2M threads
  const int4 a = ((const int4*)adj)[t * 2];
  const int4 b = ((const int4*)adj)[t * 2 + 1];
  unsigned v = (a.x > 0) | ((a.y > 0) << 1) | ((a.z > 0) << 2) | ((a.w > 0) << 3) |
               ((b.x > 0) << 4) | ((b.y > 0) << 5) | ((b.z > 0) << 6) | ((b.w > 0) << 7);
  mask8[t] = (unsigned char)v;
}

// ---- K0b: x fp32 -> fp16 ----
__global__ __launch_bounds__(256) void k_cvt_x(const float* __restrict__ x,
                                               f16_t* __restrict__ xh) {
  const int t = blockIdx.x * 256 + threadIdx.x;
  const f32x4 a = ((const f32x4*)x)[t * 2];
  const f32x4 b = ((const f32x4*)x)[t * 2 + 1];
  f16x8 o;
#pragma unroll
  for (int i = 0; i < 4; ++i) { o[i] = (f16_t)a[i]; o[i + 4] = (f16_t)b[i]; }
  ((f16x8*)xh)[t] = o;
}

// ---- K0c: W [h][k][o] fp32 -> WT [h][o][k] fp16 ----
__global__ __launch_bounds__(256) void k_cvt_w(const float* __restrict__ W,
                                               f16_t* __restrict__ WT) {
  const int t = blockIdx.x * 256 + threadIdx.x;  // 524288
  const int k = t & 511, o = (t >> 9) & 127, h = t >> 16;
  WT[t] = (f16_t)W[((h << 9) + k) * 128 + o];
}

// ---- K1: Wh = x@W per head (fp16 MFMA). Store WhB pre-swizzled in PV
// B-fragment order; epilogue computes piecewise-exp tables
// EA=2^(fs*L), EA2=2^(0.2*fs*L), EB=2^(fd*L), EB2=2^(0.2*fd*L) as fp16.
__global__ __launch_bounds__(256) void k_gemm_wh(const f16_t* __restrict__ xh,
                                                 const f16_t* __restrict__ WT,
                                                 const float* __restrict__ a_src,
                                                 const float* __restrict__ a_dst,
                                                 f16_t* __restrict__ WhB,
                                                 f16_t* __restrict__ EA,
                                                 f16_t* __restrict__ EA2,
                                                 f16_t* __restrict__ EB,
                                                 f16_t* __restrict__ EB2) {
  const int h = blockIdx.y;
  const int n0 = blockIdx.x * 64;
  const int lane = threadIdx.x & 63;
  const int w = threadIdx.x >> 6;
  const int col = lane & 15;
  const int kg = lane >> 4;
  const f16_t* xrow = xh + (size_t)(n0 + w * 16 + col) * 512 + kg * 8;
  const f16_t* wb = WT + ((size_t)h << 16) + (size_t)col * 512 + kg * 8;
  f32x4 acc[8] = {};
  for (int kk = 0; kk < 512; kk += 32) {
    const f16x8 a = *(const f16x8*)(xrow + kk);
#pragma unroll
    for (int ot = 0; ot < 8; ++ot) {
      const f16x8 b = *(const f16x8*)(wb + ot * (16 * 512) + kk);
      acc[ot] = __builtin_amdgcn_mfma_f32_16x16x32_f16(a, b, acc[ot], 0, 0, 0);
    }
  }
  float ps[4] = {0.f, 0.f, 0.f, 0.f}, pd[4] = {0.f, 0.f, 0.f, 0.f};
#pragma unroll
  for (int ot = 0; ot < 8; ++ot) {
    const float as = a_src[h * 128 + ot * 16 + col];
    const float ad = a_dst[h * 128 + ot * 16 + col];
#pragma unroll
    for (int r = 0; r < 4; ++r) { ps[r] += acc[ot][r] * as; pd[r] += acc[ot][r] * ad; }
  }
#pragma unroll
  for (int m = 1; m < 16; m <<= 1) {
#pragma unroll
    for (int r = 0; r < 4; ++r) {
      ps[r] += __shfl_xor(ps[r], m, 64);
      pd[r] += __shfl_xor(pd[r], m, 64);
    }
  }
  const int nb = n0 + w * 16 + kg * 4;  // node index of acc[.][0]
  if (col == 0) {
#pragma unroll
    for (int r = 0; r < 4; ++r) {
      const float fs = ps[r] * LOG2E;
      const float fd = pd[r] * LOG2E;
      const int idx = h * 4096 + nb + r;
      EA[idx] = (f16_t)__builtin_amdgcn_exp2f(fs);
      EA2[idx] = (f16_t)__builtin_amdgcn_exp2f(0.2f * fs);
      EB[idx] = (f16_t)__builtin_amdgcn_exp2f(fd);
      EB2[idx] = (f16_t)__builtin_amdgcn_exp2f(0.2f * fd);
    }
  }
  // swizzled store: (h,o,j) -> WhB[((h*128+j/32)*8+o/16)*512 + ((j>>3)&3)*128 + (o&15)*8 + (j&7)]
  const int jb = nb >> 5;
  const int kgt = (nb >> 3) & 3;
  const int e0 = nb & 4;
  const size_t base = ((size_t)(h * 128 + jb) * 8) * 512 + kgt * 128 + col * 8 + e0;
#pragma unroll
  for (int ot = 0; ot < 8; ++ot) {
    f16x4 v;
#pragma unroll
    for (int r = 0; r < 4; ++r) v[r] = (f16_t)acc[ot][r];
    *(f16x4*)(WhB + base + ot * 512) = v;
  }
}

// ---- K2: masked softmax-numerator + PV partials, o-split across waves ----
// Block = 4 waves sharing 64 rows; wave w owns o-quarter (2 B-frags reused
// over 4 row-groups). Mask tile (16KB) staged in LDS once (pitch 272 ->
// conflict-light b128 reads); 16-entry nibble LUTs (bank-conflict-free b64).
// B/EB register-prefetched 1 iter ahead. den fdot2 on wave 0 only.
__global__ __launch_bounds__(256, 4) void k_pv(const f16_t* __restrict__ WhB,
                                               const f16_t* __restrict__ EA,
                                               const f16_t* __restrict__ EA2,
                                               const f16_t* __restrict__ EB,
                                               const f16_t* __restrict__ EB2,
                                               const unsigned char* __restrict__ mask,
                                               f16_t* __restrict__ num_ws,
                                               float* __restrict__ den_ws) {
  __shared__ __align__(16) unsigned char lds_mask[64 * 272];
  __shared__ __align__(16) unsigned short lut4[16][4];
  const int bx = blockIdx.x;
  const int h = bx & 7;                  // head -> XCD round-robin
  const int i0 = ((bx >> 3) & 63) * 64;  // 64-row i-tile
  const int s = bx >> 9;                 // j-slice (0..1)
  const int jbeg = s * 2048;
  // stage mask tile: 64 rows x 256B, one-time coalesced copy
  {
    const int t = threadIdx.x;
    if (t < 16) {
#pragma unroll
      for (int e = 0; e < 4; ++e) lut4[t][e] = ((t >> e) & 1) ? 0x3C00 : 0;
    }
    const int row = t >> 2, ch = (t & 3) * 64;
    const uint4* src = (const uint4*)(mask + (size_t)(i0 + row) * 512 + (jbeg >> 3) + ch);
    uint4* dst = (uint4*)(lds_mask + row * 272 + ch);
#pragma unroll
    for (int i = 0; i < 4; ++i) dst[i] = src[i];
  }
  __syncthreads();
  const int lane = threadIdx.x & 63;
  const int w = threadIdx.x >> 6;        // o-quarter
  const int col = lane & 15, kg = lane >> 4;
  const bool w0 = (w == 0);
  const int sh = kg * 8;
  f16x2 As[4], A2s[4];
#pragma unroll
  for (int g = 0; g < 4; ++g) {
    const f16_t a = EA[h * 4096 + i0 + g * 16 + col];
    const f16_t a2 = EA2[h * 4096 + i0 + g * 16 + col];
    As[g] = (f16x2){a, a};
    A2s[g] = (f16x2){a2, a2};
  }
  const f16_t* EBp = EB + h * 4096 + jbeg + kg * 8;
  const f16_t* EB2p = EB2 + h * 4096 + jbeg + kg * 8;
  const f16_t* whB = WhB + ((size_t)h << 19) + (size_t)(jbeg >> 5) * 4096 + (2 * w) * 512 + lane * 8;
  f32x4 acc[4][2] = {};
  float den_s[4] = {0.f, 0.f, 0.f, 0.f};
  const f16x2 ones2 = {(f16_t)1.0f, (f16_t)1.0f};
  // prefetch iter 0
  f16x8 cb0 = *(const f16x8*)(whB);
  f16x8 cb1 = *(const f16x8*)(whB + 512);
  f16x8 cvb = *(const f16x8*)(EBp);
  f16x8 cvb2 = *(const f16x8*)(EB2p);
  for (int it4 = 0; it4 < 16; ++it4) {
    uint4 md[4];
#pragma unroll
    for (int g = 0; g < 4; ++g) {
      md[g] = *(const uint4*)(lds_mask + (g * 16 + col) * 272 + it4 * 16);
    }
#pragma unroll
    for (int q = 0; q < 4; ++q) {
      const int itn = (it4 * 4 + q + 1) & 63;
      const f16_t* wpn = whB + (size_t)itn * 4096;
      const f16x8 nb0 = *(const f16x8*)(wpn);
      const f16x8 nb1 = *(const f16x8*)(wpn + 512);
      const f16x8 nvb = *(const f16x8*)(EBp + itn * 32);
      const f16x8 nvb2 = *(const f16x8*)(EB2p + itn * 32);
      const f16x2* vbp = (const f16x2*)&cvb;
      const f16x2* vb2p = (const f16x2*)&cvb2;
      f16x8 ag[4];
#pragma unroll
      for (int g = 0; g < 4; ++g) {
        const unsigned mw = (q == 0) ? md[g].x : (q == 1) ? md[g].y : (q == 2) ? md[g].z : md[g].w;
        const unsigned bb = (mw >> sh) & 255u;
        const f16x4 lmL = *(const f16x4*)(&lut4[bb & 15u][0]);
        const f16x4 lmH = *(const f16x4*)(&lut4[bb >> 4][0]);
        const f16x2 p0 = __builtin_elementwise_max(As[g] * vbp[0], A2s[g] * vb2p[0]) * ((const f16x2*)&lmL)[0];
        const f16x2 p1 = __builtin_elementwise_max(As[g] * vbp[1], A2s[g] * vb2p[1]) * ((const f16x2*)&lmL)[1];
        const f16x2 p2 = __builtin_elementwise_max(As[g] * vbp[2], A2s[g] * vb2p[2]) * ((const f16x2*)&lmH)[0];
        const f16x2 p3 = __builtin_elementwise_max(As[g] * vbp[3], A2s[g] * vb2p[3]) * ((const f16x2*)&lmH)[1];
        f16x8 a;
        ((f16x2*)&a)[0] = p0;
        ((f16x2*)&a)[1] = p1;
        ((f16x2*)&a)[2] = p2;
        ((f16x2*)&a)[3] = p3;
        ag[g] = a;
        if (w0) {
          den_s[g] = __builtin_amdgcn_fdot2(p0, ones2, den_s[g], false);
          den_s[g] = __builtin_amdgcn_fdot2(p1, ones2, den_s[g], false);
          den_s[g] = __builtin_amdgcn_fdot2(p2, ones2, den_s[g], false);
          den_s[g] = __builtin_amdgcn_fdot2(p3, ones2, den_s[g], false);
        }
      }
#pragma unroll
      for (int g = 0; g < 4; ++g) {
        acc[g][0] = __builtin_amdgcn_mfma_f32_16x16x32_f16(ag[g], cb0, acc[g][0], 0, 0, 0);
        acc[g][1] = __builtin_amdgcn_mfma_f32_16x16x32_f16(ag[g], cb1, acc[g][1], 0, 0, 0);
      }
      cb0 = nb0; cb1 = nb1; cvb = nvb; cvb2 = nvb2;
    }
  }
  // den: wave 0 only (wave-invariant); reduce over kg, lane col writes row.
  if (w0) {
#pragma unroll
    for (int g = 0; g < 4; ++g) {
      float d = den_s[g];
      d += __shfl_xor(d, 16, 64);
      d += __shfl_xor(d, 32, 64);
      if (kg == 0) {
        den_ws[(size_t)(s * 8 + h) * 4096 + i0 + g * 16 + col] = d;
      }
    }
  }
  // num partials: D frag row = g*16 + kg*4 + r, col o = w*32 + t*16 + col
  f16_t* np = num_ws + ((size_t)(s * 8 + h) * 4096 + i0) * 128;
#pragma unroll
  for (int g = 0; g < 4; ++g) {
#pragma unroll
    for (int t = 0; t < 2; ++t) {
#pragma unroll
      for (int r = 0; r < 4; ++r) {
        np[(g * 16 + kg * 4 + r) * 128 + w * 32 + t * 16 + col] = (f16_t)acc[g][t][r];
      }
    }
  }
}

// ---- K3: merge slices + normalize -> out[n][h*128+o] fp32 ----
__global__ __launch_bounds__(256) void k_merge(const f16_t* __restrict__ num_ws,
                                               const float* __restrict__ den_ws,
                                               float* __restrict__ out, int nslice) {
  const int g4 = (blockIdx.x * 256 + threadIdx.x) * 4;
  const int o = g4 & 127, h = (g4 >> 7) & 7, n = g4 >> 10;
  f32x4 sum = {};
  float d = 0.f;
  for (int sl = 0; sl < nslice; ++sl) {
    const f16x4 v = *(const f16x4*)(num_ws + ((size_t)((sl * 8 + h) * 4096) + n) * 128 + o);
#pragma unroll
    for (int i = 0; i < 4; ++i) sum[i] += (float)v[i];
    d += den_ws[(size_t)(sl * 8 + h) * 4096 + n];
  }
  const float inv = __builtin_amdgcn_rcpf(d);
  f32x4 r;
#pragma unroll
  for (int i = 0; i < 4; ++i) r[i] = sum[i] * inv;
  *(f32x4*)(out + g4) = r;
}

extern "C" void kernel_launch(void* const* d_in, const int* in_sizes, int n_in,
                              void* d_out, int out_size, void* d_ws, size_t ws_size,
                              hipStream_t stream) {
  const float* x = (const float*)d_in[0];
  const int* adj = (const int*)d_in[1];
  const float* W = (const float*)d_in[2];
  const float* a_src = (const float*)d_in[3];
  const float* a_dst = (const float*)d_in[4];
  float* out = (float*)d_out;
  char* ws = (char*)d_ws;
  // workspace layout (bytes):
  //   WhB   swizzled f16          : 0        .. 8388608
  //   xh    [4096][512] f16       : 8388608  .. 12582912
  //   WT    [8][128][512] f16     : 12582912 .. 13631488
  //   mask  [4096][512] u8        : 13631488 .. 15728640
  //   EA/EA2/EB/EB2 [8][4096] f16 : 15728640 .. 15990784 (4 x 64KB)
  //   den_ws [2][8][4096] f32     : 15990784 .. 16252928
  //   num_ws [2][8][4096][128] f16: 16252928 .. 33030144
  const size_t FIXED = 15990784;
  f16_t* WhB = (f16_t*)(ws);
  f16_t* xh = (f16_t*)(ws + 8388608);
  f16_t* WT = (f16_t*)(ws + 12582912);
  unsigned char* mask8 = (unsigned char*)(ws + 13631488);
  f16_t* EA = (f16_t*)(ws + 15728640);
  f16_t* EA2 = (f16_t*)(ws + 15794176);
  f16_t* EB = (f16_t*)(ws + 15859712);
  f16_t* EB2 = (f16_t*)(ws + 15925248);
  float* den_ws = (float*)(ws + FIXED);
  f16_t* num_ws = (f16_t*)(ws + FIXED + 262144);

  k_pack_adj<<<8192, 256, 0, stream>>>(adj, mask8);
  k_cvt_x<<<1024, 256, 0, stream>>>(x, xh);
  k_cvt_w<<<2048, 256, 0, stream>>>(W, WT);
  k_gemm_wh<<<dim3(64, 8), 256, 0, stream>>>(xh, WT, a_src, a_dst, WhB, EA, EA2, EB, EB2);
  k_pv<<<1024, 256, 0, stream>>>(WhB, EA, EA2, EB, EB2, mask8, num_ws, den_ws);
  k_merge<<<4096, 256, 0, stream>>>(num_ws, den_ws, out, 2);
}